// Round 10
// baseline (187.228 us; speedup 1.0000x reference)
//
#include <hip/hip_runtime.h>
#include <math.h>

#define M_ 3
#define B_ 128
#define T_ 512
#define D_ 1024
#define P_ 256
#define TC 2            // t-chunks for the pooling kernel

#define NPOOL   (M_ * B_ * TC)     // 768 pool blocks
#define NW1T    192                // W1-transpose rider blocks (4 tiles each)
#define NW2     64                 // W2 cast rider blocks
// total 1024 blocks = exactly 4 blocks/CU co-resident

typedef __attribute__((ext_vector_type(8))) short short8v;   // 8 bf16 (4 VGPRs)
typedef __attribute__((ext_vector_type(4))) float f32x4;

// bf16 round-to-nearest-even from f32 bits
__device__ __forceinline__ unsigned int f2bf(float f) {
    unsigned int x = __float_as_uint(f);
    return (x + 0x7fffu + ((x >> 16) & 1u)) >> 16;
}

// nontemporal float4 load via native ext-vector type (builtin rejects HIP_vector_type)
__device__ __forceinline__ float4 ntload4(const float4* p) {
    f32x4 v = __builtin_nontemporal_load((const f32x4*)p);
    return make_float4(v.x, v.y, v.z, v.w);
}

// ---------------- Kernel 1: pool partials + W1^T-bf16 + W2-bf16 riders ----------------
// Pool: wave w of block (mb,tc) owns 64 CONSECUTIVE timesteps and reads each 4KB
// timestep row ENTIRELY itself (4 loads: cols l, l+64, l+128, l+192) -> every
// DRAM row is opened once by one wave (no cross-wave fragmentation). Per-wave
// sums combined across the 4 waves via an LDS epilogue.
__global__ __launch_bounds__(256) void pool_and_cast(const float* __restrict__ feats,
                                                     const float* __restrict__ W1,
                                                     const float* __restrict__ W2,
                                                     float* __restrict__ partial,
                                                     short* __restrict__ w1t,
                                                     unsigned int* __restrict__ w2p) {
    __shared__ float  ldsf[64][68];     // rider transpose buffer (17 KB)
    __shared__ float4 red[4][256];      // pool epilogue buffer (16 KB)
    int blk = blockIdx.x;
    int tid = threadIdx.x;

    if (blk < NPOOL) {
        int tc = blk & (TC - 1);
        int mb = blk / TC;
        int l  = tid & 63;
        int w  = tid >> 6;
        const int LDQ   = D_ / 4;               // 256 float4 per timestep
        const int TSTEP = T_ / TC;              // 256
        const int WT    = TSTEP / 4;            // 64 timesteps per wave
        const float4* base = (const float4*)feats
            + ((size_t)mb * T_ + (size_t)tc * TSTEP + (size_t)w * WT) * LDQ;

        float4 a0 = make_float4(0.f, 0.f, 0.f, 0.f);
        float4 a1 = a0, a2 = a0, a3 = a0;
        float4 b0 = a0, b1 = a0, b2 = a0, b3 = a0;
        for (int t = 0; t < WT; t += 2) {
            const float4* r0 = base + (size_t)t * LDQ;
            const float4* r1 = r0 + LDQ;
            float4 v0 = ntload4(r0 + l);
            float4 v1 = ntload4(r0 + l + 64);
            float4 v2 = ntload4(r0 + l + 128);
            float4 v3 = ntload4(r0 + l + 192);
            float4 u0 = ntload4(r1 + l);
            float4 u1 = ntload4(r1 + l + 64);
            float4 u2 = ntload4(r1 + l + 128);
            float4 u3 = ntload4(r1 + l + 192);
            a0.x += v0.x; a0.y += v0.y; a0.z += v0.z; a0.w += v0.w;
            a1.x += v1.x; a1.y += v1.y; a1.z += v1.z; a1.w += v1.w;
            a2.x += v2.x; a2.y += v2.y; a2.z += v2.z; a2.w += v2.w;
            a3.x += v3.x; a3.y += v3.y; a3.z += v3.z; a3.w += v3.w;
            b0.x += u0.x; b0.y += u0.y; b0.z += u0.z; b0.w += u0.w;
            b1.x += u1.x; b1.y += u1.y; b1.z += u1.z; b1.w += u1.w;
            b2.x += u2.x; b2.y += u2.y; b2.z += u2.z; b2.w += u2.w;
            b3.x += u3.x; b3.y += u3.y; b3.z += u3.z; b3.w += u3.w;
        }
        a0.x += b0.x; a0.y += b0.y; a0.z += b0.z; a0.w += b0.w;
        a1.x += b1.x; a1.y += b1.y; a1.z += b1.z; a1.w += b1.w;
        a2.x += b2.x; a2.y += b2.y; a2.z += b2.z; a2.w += b2.w;
        a3.x += b3.x; a3.y += b3.y; a3.z += b3.z; a3.w += b3.w;

        red[w][l]       = a0;
        red[w][l + 64]  = a1;
        red[w][l + 128] = a2;
        red[w][l + 192] = a3;
        __syncthreads();
        float4 s0 = red[0][tid], s1 = red[1][tid], s2 = red[2][tid], s3 = red[3][tid];
        float4 s;
        s.x = (s0.x + s1.x) + (s2.x + s3.x);
        s.y = (s0.y + s1.y) + (s2.y + s3.y);
        s.z = (s0.z + s1.z) + (s2.z + s3.z);
        s.w = (s0.w + s1.w) + (s2.w + s3.w);
        ((float4*)partial)[((size_t)mb * TC + tc) * (D_ / 4) + tid] = s;
        return;
    }

    if (blk < NPOOL + NW1T) {
        // W1 [m][k][e] f32  ->  w1t [m][e][k] bf16 ; 64x64 tiles via LDS transpose
        int bid = blk - NPOOL;                 // 0..191
        for (int i = 0; i < 4; ++i) {
            int tile = bid * 4 + i;            // 0..767
            int et = tile & 15;
            int kt = (tile >> 4) & 15;
            int mm = tile >> 8;
            int k0 = kt * 64, ee0 = et * 64;
#pragma unroll
            for (int sv = 0; sv < 4; ++sv) {
                int idx = sv * 256 + tid;
                int row = idx >> 4;
                int c4  = idx & 15;
                float4 v = ntload4((const float4*)(W1 + (size_t)mm * D_ * D_ + (size_t)(k0 + row) * D_ + ee0 + c4 * 4));
                *(float4*)&ldsf[row][c4 * 4] = v;
            }
            __syncthreads();
            int er = tid >> 2;
            int ks = (tid & 3) * 16;
            short8v v0, v1;
#pragma unroll
            for (int j = 0; j < 8; ++j) v0[j] = (short)f2bf(ldsf[ks + j][er]);
#pragma unroll
            for (int j = 0; j < 8; ++j) v1[j] = (short)f2bf(ldsf[ks + 8 + j][er]);
            size_t ob = ((size_t)mm * D_ + ee0 + er) * D_ + k0 + ks;
            *(short8v*)(w1t + ob)     = v0;
            *(short8v*)(w1t + ob + 8) = v1;
            __syncthreads();
        }
        return;
    }

    // W2 cast: w2p[m][k2][p] = bf16(W2[m][2k2][p]) | bf16(W2[m][2k2+1][p])<<16
    {
        int bid = blk - NPOOL - NW1T;          // 0..63
        const int TOT = M_ * (D_ / 2) * P_;    // 393216
        for (int i = bid * 256 + tid; i < TOT; i += NW2 * 256) {
            int p  = i & (P_ - 1);
            int k2 = (i >> 8) & (D_ / 2 - 1);
            int m  = i >> 17;
            size_t base = (size_t)m * D_ * P_ + (size_t)(2 * k2) * P_ + p;
            float f0 = __builtin_nontemporal_load(W2 + base);
            float f1 = __builtin_nontemporal_load(W2 + base + P_);
            w2p[i] = f2bf(f0) | (f2bf(f1) << 16);
        }
    }
}

// ---------------- Kernel 2: h = gelu(mean(partial) @ W1 + b1), bf16 MFMA ----------------
// grid (D/64=16, B/32=4, M) = 192 blocks, 256 threads = 4 waves.
// Tile 32(rows) x 64(cols), BK=64. LDS XOR-swizzled (16B chunk ^= row&7).
__global__ __launch_bounds__(256) void gemm1_mfma(const float* __restrict__ partial,
                                                  const short* __restrict__ w1t,
                                                  const float* __restrict__ b1,
                                                  float* __restrict__ h) {
    __shared__ __align__(16) short As[32 * 64];   // [row][k] bf16, 128B rows
    __shared__ __align__(16) short Bs[64 * 64];   // [col][k] bf16, 128B rows
    int m  = blockIdx.z;
    int b0 = blockIdx.y * 32;
    int e0 = blockIdx.x * 64;
    int tid = threadIdx.x;
    int l   = tid & 63;
    int w   = tid >> 6;
    int wr  = w & 1, wc = w >> 1;

    int arow = tid >> 3;          // 0..31 A row
    int k8   = tid & 7;           // 16B chunk (8 bf16)
    int bcol = tid >> 2;          // 0..63 B "row" (= W1 col)
    int bj   = tid & 3;           // 32B segment (2 chunks)

    const float* Abase = partial + ((size_t)(m * B_ + b0 + arow) * TC) * D_ + k8 * 8;
    const short* Bbase = w1t + ((size_t)m * D_ + e0 + bcol) * D_ + bj * 16;

    char* AsB = (char*)As;
    char* BsB = (char*)Bs;
    short8v* AsW  = (short8v*)(AsB + arow * 128 + ((k8 ^ (arow & 7)) << 4));
    short8v* BsW0 = (short8v*)(BsB + bcol * 128 + (((2 * bj)     ^ (bcol & 7)) << 4));
    short8v* BsW1 = (short8v*)(BsB + bcol * 128 + (((2 * bj + 1) ^ (bcol & 7)) << 4));

    f32x4 acc0 = {0.f, 0.f, 0.f, 0.f};
    f32x4 acc1 = {0.f, 0.f, 0.f, 0.f};
    const float inv = 1.0f / (float)T_;

    int ar  = wr * 16 + (l & 15);
    int bc0 = wc * 32 + (l & 15);
    int bc1 = bc0 + 16;
    int lh  = l >> 4;             // 0..3

    for (int it = 0; it < 16; ++it) {
        int k0 = it * 64;
        float4 p00 = *(const float4*)(Abase + k0);
        float4 p01 = *(const float4*)(Abase + k0 + 4);
        float4 p10 = *(const float4*)(Abase + D_ + k0);
        float4 p11 = *(const float4*)(Abase + D_ + k0 + 4);
        short8v bv0 = *(const short8v*)(Bbase + k0);
        short8v bv1 = *(const short8v*)(Bbase + k0 + 8);
        __syncthreads();   // previous iteration's frag reads done
        short8v av;
        av[0] = (short)f2bf((p00.x + p10.x) * inv);
        av[1] = (short)f2bf((p00.y + p10.y) * inv);
        av[2] = (short)f2bf((p00.z + p10.z) * inv);
        av[3] = (short)f2bf((p00.w + p10.w) * inv);
        av[4] = (short)f2bf((p01.x + p11.x) * inv);
        av[5] = (short)f2bf((p01.y + p11.y) * inv);
        av[6] = (short)f2bf((p01.z + p11.z) * inv);
        av[7] = (short)f2bf((p01.w + p11.w) * inv);
        *AsW  = av;
        *BsW0 = bv0;
        *BsW1 = bv1;
        __syncthreads();
#pragma unroll
        for (int kk = 0; kk < 2; ++kk) {
            int ch = kk * 4 + lh;
            short8v af  = *(const short8v*)(AsB + ar  * 128 + ((ch ^ (ar  & 7)) << 4));
            short8v bf0 = *(const short8v*)(BsB + bc0 * 128 + ((ch ^ (bc0 & 7)) << 4));
            short8v bf1 = *(const short8v*)(BsB + bc1 * 128 + ((ch ^ (bc1 & 7)) << 4));
            acc0 = __builtin_amdgcn_mfma_f32_16x16x32_bf16(af, bf0, acc0, 0, 0, 0);
            acc1 = __builtin_amdgcn_mfma_f32_16x16x32_bf16(af, bf1, acc1, 0, 0, 0);
        }
    }

    // epilogue: C/D layout col=lane&15, row=(lane>>4)*4+reg  [m89-verified]
    int colBase = e0 + wc * 32 + (l & 15);
    int rowBase = b0 + wr * 16 + lh * 4;
    const float is2 = 0.70710678118654752f;
#pragma unroll
    for (int n = 0; n < 2; ++n) {
        f32x4 acc = n ? acc1 : acc0;
        int col = colBase + n * 16;
        float bb = b1[m * D_ + col];
#pragma unroll
        for (int r = 0; r < 4; ++r) {
            float x = acc[r] + bb;
            float gx = 0.5f * x * (1.0f + erff(x * is2));
            h[(size_t)(m * B_ + rowBase + r) * D_ + col] = gx;
        }
    }
}

// ---------------- Kernel 3: z = h @ W2 + b2, LN, L2-normalize; split-K x2, 512 thr ----------------
__global__ __launch_bounds__(512) void gemm2_ln(const float* __restrict__ h,
                                                const unsigned int* __restrict__ w2p,
                                                const float* __restrict__ b2,
                                                const float* __restrict__ gamma,
                                                const float* __restrict__ beta,
                                                float* __restrict__ out) {
    int m  = blockIdx.y;
    int b0 = blockIdx.x * 2;
    int tid  = threadIdx.x;
    int p    = tid & 255;
    int half = tid >> 8;
    int lane = tid & 63;
    int w    = (tid >> 6) & 3;

    __shared__ float accs[2][2][256];   // [half][row][p]
    __shared__ float redA[2][4];
    __shared__ float redB[2][4];
    __shared__ float redC[2][4];

    const unsigned int* Wp = w2p + (size_t)m * (D_ / 2) * P_ + (size_t)half * 256 * P_ + p;
    const float* hb = h + ((size_t)m * B_ + b0) * D_ + half * 512;

    float acc0 = 0.f, acc1 = 0.f;
#pragma unroll 8
    for (int q = 0; q < 128; ++q) {
        unsigned int u0 = Wp[(size_t)(2 * q) * P_];
        unsigned int u1 = Wp[(size_t)(2 * q + 1) * P_];
        float w0 = __uint_as_float(u0 << 16);
        float w1 = __uint_as_float(u0 & 0xffff0000u);
        float w2 = __uint_as_float(u1 << 16);
        float w3 = __uint_as_float(u1 & 0xffff0000u);
        float4 h0 = *(const float4*)(hb + 4 * q);          // uniform
        float4 h1 = *(const float4*)(hb + D_ + 4 * q);     // uniform
        acc0 += h0.x * w0 + h0.y * w1 + h0.z * w2 + h0.w * w3;
        acc1 += h1.x * w0 + h1.y * w1 + h1.z * w2 + h1.w * w3;
    }
    accs[half][0][p] = acc0;
    accs[half][1][p] = acc1;
    __syncthreads();

    int g = half;
    float z = accs[0][g][p] + accs[1][g][p] + b2[m * P_ + p];

    float s1 = z, s2 = z * z;
    for (int off = 32; off > 0; off >>= 1) {
        s1 += __shfl_xor(s1, off);
        s2 += __shfl_xor(s2, off);
    }
    if (lane == 0) { redA[g][w] = s1; redB[g][w] = s2; }
    __syncthreads();
    s1 = (redA[g][0] + redA[g][1]) + (redA[g][2] + redA[g][3]);
    s2 = (redB[g][0] + redB[g][1]) + (redB[g][2] + redB[g][3]);
    float mu  = s1 * (1.0f / P_);
    float var = s2 * (1.0f / P_) - mu * mu;
    float inv = 1.0f / sqrtf(var + 1e-5f);
    z = (z - mu) * inv * gamma[m * P_ + p] + beta[m * P_ + p];

    float s = z * z;
    for (int off = 32; off > 0; off >>= 1) s += __shfl_xor(s, off);
    if (lane == 0) redC[g][w] = s;
    __syncthreads();
    s = (redC[g][0] + redC[g][1]) + (redC[g][2] + redC[g][3]);
    float n = sqrtf(s);
    out[((size_t)m * B_ + b0 + g) * P_ + p] = z / fmaxf(n, 1e-12f);
}

extern "C" void kernel_launch(void* const* d_in, const int* in_sizes, int n_in,
                              void* d_out, int out_size, void* d_ws, size_t ws_size,
                              hipStream_t stream) {
    const float* feats = (const float*)d_in[0];
    const float* W1    = (const float*)d_in[1];
    const float* b1    = (const float*)d_in[2];
    const float* W2    = (const float*)d_in[3];
    const float* b2    = (const float*)d_in[4];
    const float* gamma = (const float*)d_in[5];
    const float* beta  = (const float*)d_in[6];
    float* out = (float*)d_out;

    float* wsf = (float*)d_ws;
    const size_t NPART = (size_t)M_ * B_ * TC * D_;              // 786432 floats (3 MB)
    float*        partial = wsf;
    unsigned int* w2p     = (unsigned int*)(wsf + NPART);        // 393216 u32 (1.5 MB)
    float*        hbuf    = wsf + NPART + 393216;                // 393216 f32 (1.5 MB)
    short*        w1t     = (short*)(wsf + NPART + 2 * 393216);  // M*D*D bf16 (6 MB)
    // total ws: 12 MB

    pool_and_cast<<<NPOOL + NW1T + NW2, 256, 0, stream>>>(feats, W1, W2, partial, w1t, w2p);
    dim3 g2(D_ / 64, B_ / 32, M_);
    gemm1_mfma<<<g2, 256, 0, stream>>>(partial, w1t, b1, hbuf);
    dim3 g3(B_ / 2, M_);
    gemm2_ln<<<g3, 512, 0, stream>>>(hbuf, w2p, b2, gamma, beta, out);
}